// Round 3
// baseline (91.663 us; speedup 1.0000x reference)
//
#include <hip/hip_runtime.h>
#include <math.h>

// LearnableLPDistance: A,B [1,8,512,64] f32, p_raw [1] f32.
// p = softplus(p_raw)+1e-10; Lp-normalize rows; out[h,n,m] = 1 - 0.5*Lp(An[n]-Bn[m]).
//
// Strategy: |x|^p via bit-sliced table lookup (exponent + top-6 mantissa -> {val, slope},
// linear interp on low 17 mantissa bits) = pure VALU, 0 trans. Half the dims use this
// path, half use hw exp2/log2 -> the trans pipe and VALU pipe run concurrently.

#define EPSF   1e-10f
#define NROW   512
#define DDIM   64
#define TSTRIDE 68     // LDS tile row stride in dwords
#define TB     32      // output tile 32x32
#define TBL_E0 108     // lowest exponent byte covered (2^-19; below -> ~0)
#define TBL_N  1344    // 21 octaves x 64 mantissa bins
#define TBL_J0 (TBL_E0 * 64)

__device__ __forceinline__ float hw_log2(float x) { return __builtin_amdgcn_logf(x); }
__device__ __forceinline__ float hw_exp2(float x) { return __builtin_amdgcn_exp2f(x); }
__device__ __forceinline__ float powp(float x, float p) { return hw_exp2(p * hw_log2(x)); }
__device__ __forceinline__ float softplusf(float x) {
    return fmaxf(x, 0.0f) + log1pf(expf(-fabsf(x)));
}

// |x|^p via table: xi = bits(|x|); j = xi>>17 indexes (e, top6-mantissa);
// interp on low 17 bits. Exact-ish (rel err <= ~6e-6) for x in [2^-19, 2].
__device__ __forceinline__ float tbl_pow(const float2* __restrict__ t, float x) {
    unsigned xi = __float_as_uint(x) & 0x7fffffffu;
    unsigned j  = xi >> 17;
    j = (j < TBL_J0) ? TBL_J0 : j;       // clamp tiny |x| -> bottom entry (~0)
    const float2 tv = t[j - TBL_J0];     // ds_read_b64
    const float dl = (float)(xi & 0x1ffffu);
    return fmaf(dl, tv.y, tv.x);
}

// Fused: blocks [0,2048) Lp-normalize rows (A then B) into ws;
//        blocks [2048,2054) build the |x|^p table from runtime p.
__global__ __launch_bounds__(256) void lp_norm_table_kernel(const float* __restrict__ A,
                                                            const float* __restrict__ B,
                                                            const float* __restrict__ p_raw,
                                                            float* __restrict__ ws,
                                                            float2* __restrict__ tbl) {
    const float p = softplusf(p_raw[0]) + EPSF;
    const int b = blockIdx.x;
    if (b >= 2048) {
        const int idx = (b - 2048) * 256 + threadIdx.x;
        if (idx < TBL_N) {
            const int e = TBL_E0 + (idx >> 6);
            const int k = idx & 63;
            const float le = (float)(e - 127);
            const float v0 = hw_exp2(p * (le + hw_log2(1.0f + (float)k * 0.015625f)));
            const float v1 = hw_exp2(p * (le + hw_log2(1.0f + (float)(k + 1) * 0.015625f)));
            tbl[idx] = make_float2(v0, (v1 - v0) * (1.0f / 131072.0f));
        }
        return;
    }
    const float inv_p = 1.0f / p;
    const int row  = b * 4 + (threadIdx.x >> 6);
    const int lane = threadIdx.x & 63;
    const float* src = (row < 4096) ? (A + (size_t)row * DDIM)
                                    : (B + (size_t)(row - 4096) * DDIM);
    const float x = src[lane];
    float t = powp(fabsf(x), p);
    #pragma unroll
    for (int m = 1; m < 64; m <<= 1) t += __shfl_xor(t, m, 64);
    const float norm = powp(t, inv_p) + EPSF;
    ws[(size_t)row * DDIM + lane] = x / norm;
}

// 32x32 tile / 256 threads; grid (16,16,8) = 2048 blocks.
// Per 8-dim chunk: dims [d,d+4) on hw trans pipe, dims [d+4,d+8) on VALU table path.
__global__ __launch_bounds__(256) void lp_pair_kernel(const float* __restrict__ ws,
                                                      const float2* __restrict__ gtbl,
                                                      const float* __restrict__ p_raw,
                                                      float* __restrict__ out) {
    __shared__ float2 s_tbl[TBL_N];                  // 10.5 KB
    __shared__ float As[TB * TSTRIDE];               // 8.5 KB
    __shared__ float Bs[TB * TSTRIDE];

    const float p     = softplusf(p_raw[0]) + EPSF;
    const float inv_p = 1.0f / p;
    const int tid = threadIdx.x;

    // Table -> LDS (one-time, coalesced b64 per lane).
    #pragma unroll
    for (int i = 0; i < 6; ++i) {
        const int idx = i * 256 + tid;
        if (idx < TBL_N) s_tbl[idx] = gtbl[idx];
    }

    const int h  = blockIdx.z;
    const int n0 = blockIdx.y * TB;
    const int m0 = blockIdx.x * TB;
    const float* An = ws + (size_t)h * NROW * DDIM;
    const float* Bn = ws + (size_t)4096 * DDIM + (size_t)h * NROW * DDIM;

    #pragma unroll
    for (int k = 0; k < 2; ++k) {
        const int qq  = k * 256 + tid;
        const int row = qq >> 4;
        const int d4  = qq & 15;
        const float4 va = *reinterpret_cast<const float4*>(An + (size_t)(n0 + row) * DDIM + d4 * 4);
        const float4 vb = *reinterpret_cast<const float4*>(Bn + (size_t)(m0 + row) * DDIM + d4 * 4);
        *reinterpret_cast<float4*>(&As[row * TSTRIDE + d4 * 4]) = va;
        *reinterpret_cast<float4*>(&Bs[row * TSTRIDE + d4 * 4]) = vb;
    }
    __syncthreads();

    const int tn = tid >> 4;   // 0..15
    const int tm = tid & 15;   // 0..15

    float acc00 = 0.f, acc01 = 0.f, acc10 = 0.f, acc11 = 0.f;

    #pragma unroll
    for (int d = 0; d < DDIM; d += 8) {
        // trans-path dims [d, d+4)
        const float4 a0 = *reinterpret_cast<const float4*>(&As[tn * TSTRIDE + d]);
        const float4 a1 = *reinterpret_cast<const float4*>(&As[(tn + 16) * TSTRIDE + d]);
        const float4 b0 = *reinterpret_cast<const float4*>(&Bs[tm * TSTRIDE + d]);
        const float4 b1 = *reinterpret_cast<const float4*>(&Bs[(tm + 16) * TSTRIDE + d]);
        // table-path dims [d+4, d+8)
        const float4 av0 = *reinterpret_cast<const float4*>(&As[tn * TSTRIDE + d + 4]);
        const float4 av1 = *reinterpret_cast<const float4*>(&As[(tn + 16) * TSTRIDE + d + 4]);
        const float4 bv0 = *reinterpret_cast<const float4*>(&Bs[tm * TSTRIDE + d + 4]);
        const float4 bv1 = *reinterpret_cast<const float4*>(&Bs[(tm + 16) * TSTRIDE + d + 4]);

        acc00 += powp(fabsf(a0.x - b0.x), p); acc00 += powp(fabsf(a0.y - b0.y), p);
        acc00 += powp(fabsf(a0.z - b0.z), p); acc00 += powp(fabsf(a0.w - b0.w), p);
        acc01 += powp(fabsf(a0.x - b1.x), p); acc01 += powp(fabsf(a0.y - b1.y), p);
        acc01 += powp(fabsf(a0.z - b1.z), p); acc01 += powp(fabsf(a0.w - b1.w), p);
        acc10 += powp(fabsf(a1.x - b0.x), p); acc10 += powp(fabsf(a1.y - b0.y), p);
        acc10 += powp(fabsf(a1.z - b0.z), p); acc10 += powp(fabsf(a1.w - b0.w), p);
        acc11 += powp(fabsf(a1.x - b1.x), p); acc11 += powp(fabsf(a1.y - b1.y), p);
        acc11 += powp(fabsf(a1.z - b1.z), p); acc11 += powp(fabsf(a1.w - b1.w), p);

        acc00 += tbl_pow(s_tbl, av0.x - bv0.x); acc00 += tbl_pow(s_tbl, av0.y - bv0.y);
        acc00 += tbl_pow(s_tbl, av0.z - bv0.z); acc00 += tbl_pow(s_tbl, av0.w - bv0.w);
        acc01 += tbl_pow(s_tbl, av0.x - bv1.x); acc01 += tbl_pow(s_tbl, av0.y - bv1.y);
        acc01 += tbl_pow(s_tbl, av0.z - bv1.z); acc01 += tbl_pow(s_tbl, av0.w - bv1.w);
        acc10 += tbl_pow(s_tbl, av1.x - bv0.x); acc10 += tbl_pow(s_tbl, av1.y - bv0.y);
        acc10 += tbl_pow(s_tbl, av1.z - bv0.z); acc10 += tbl_pow(s_tbl, av1.w - bv0.w);
        acc11 += tbl_pow(s_tbl, av1.x - bv1.x); acc11 += tbl_pow(s_tbl, av1.y - bv1.y);
        acc11 += tbl_pow(s_tbl, av1.z - bv1.z); acc11 += tbl_pow(s_tbl, av1.w - bv1.w);
    }

    float* outh = out + (size_t)h * NROW * NROW;
    const int n_lo = n0 + tn, n_hi = n0 + tn + 16;
    const int m_lo = m0 + tm, m_hi = m0 + tm + 16;
    outh[(size_t)n_lo * NROW + m_lo] = 1.0f - 0.5f * powp(acc00, inv_p);
    outh[(size_t)n_lo * NROW + m_hi] = 1.0f - 0.5f * powp(acc01, inv_p);
    outh[(size_t)n_hi * NROW + m_lo] = 1.0f - 0.5f * powp(acc10, inv_p);
    outh[(size_t)n_hi * NROW + m_hi] = 1.0f - 0.5f * powp(acc11, inv_p);
}

extern "C" void kernel_launch(void* const* d_in, const int* in_sizes, int n_in,
                              void* d_out, int out_size, void* d_ws, size_t ws_size,
                              hipStream_t stream) {
    const float* A     = (const float*)d_in[0];
    const float* B     = (const float*)d_in[1];
    const float* p_raw = (const float*)d_in[2];
    float* out = (float*)d_out;
    float* ws  = (float*)d_ws;                          // [8192][64] normalized rows (2 MB)
    float2* tbl = (float2*)(ws + (size_t)8192 * DDIM);  // 1344 x float2 after rows

    lp_norm_table_kernel<<<dim3(2054), dim3(256), 0, stream>>>(A, B, p_raw, ws, tbl);
    lp_pair_kernel<<<dim3(16, 16, 8), dim3(256), 0, stream>>>(ws, tbl, p_raw, out);
}